// Round 1
// baseline (785.381 us; speedup 1.0000x reference)
//
#include <hip/hip_runtime.h>
#include <math.h>

// MemoryBank: B=64, C=1501, D=2048, fp32
//   out0 selected     [B,D]    = memory[cls_list]            (original memory)
//   out1 tmp_repeated [B,C,D]  = B copies of tmp_memory      (memory w/ rows cls_list <- x, last-write-wins)
//   out2 new_mem      [C,D]    = l2normalize(memory*(1-a) + tmp_memory*a)
//
// R1 restructure: out1[b=0] IS tmp_memory. Kernel A writes slab 0 + selected +
// new_mem (plain cached stores). Kernel B replicates slab 0 -> slabs 1..63 in a
// fill-shaped pattern (contiguous rows, plain stores, reads served by MALL).
// NT stores removed: the 6.27 TB/s rocclr fill uses plain stores; our NT path
// measured only ~3.0 TB/s effective.

#define ALPHA 0.01f
#define EPS_  1e-7f
#define B_    64
#define C_    1501
#define D_    2048
#define T_    256          // threads per block; D_/4 = 512 float4 = 2 per thread
#define REP_PER_BLK 7      // 63 replicated slabs = 7 * 9
#define REP_GRID_Y  9

// clang-native vector type
typedef float f32x4 __attribute__((ext_vector_type(4)));

// ---------------------------------------------------------------------------
// Kernel A: per class row c — mask/winner, selected rows, new_mem, tmp row
// into out1 slab b=0 (cacheable, so kernel B re-reads it from L2/MALL).
// ---------------------------------------------------------------------------
__global__ __launch_bounds__(T_) void mb_prep(
    const float* __restrict__ x,    // [B,D]
    const int*   __restrict__ cls,  // [B]
    const float* __restrict__ mem,  // [C,D]
    float*       __restrict__ out)  // [B*D + B*C*D + C*D]
{
    const int c   = blockIdx.x;
    const int tid = threadIdx.x;

    // which b's (if any) map to this row; winner = max b (last write wins)
    __shared__ unsigned long long s_mask;
    if (tid < 64) {
        int cb = cls[tid];
        unsigned long long m = __ballot(cb == c);
        if (tid == 0) s_mask = m;
    }
    __syncthreads();
    const unsigned long long mask = s_mask;
    const int winner = mask ? (63 - __clzll(mask)) : -1;

    // load memory row (2 float4 per thread, coalesced)
    const f32x4* mrow = (const f32x4*)(mem + (size_t)c * D_);
    f32x4 m0 = mrow[tid];
    f32x4 m1 = mrow[tid + T_];

    // tmp_memory row: x[winner] if scattered into, else memory row
    f32x4 t0 = m0, t1 = m1;
    if (winner >= 0) {
        const f32x4* xrow = (const f32x4*)(x + (size_t)winner * D_);
        t0 = xrow[tid];
        t1 = xrow[tid + T_];
    }

    // EMA row
    f32x4 n0 = m0 * (1.0f - ALPHA) + t0 * ALPHA;
    f32x4 n1 = m1 * (1.0f - ALPHA) + t1 * ALPHA;

    // row L2 norm: per-thread partial -> wave64 butterfly -> LDS across 4 waves
    float ss = n0.x*n0.x + n0.y*n0.y + n0.z*n0.z + n0.w*n0.w
             + n1.x*n1.x + n1.y*n1.y + n1.z*n1.z + n1.w*n1.w;
    #pragma unroll
    for (int off = 32; off > 0; off >>= 1)
        ss += __shfl_xor(ss, off, 64);
    __shared__ float s_part[T_ / 64];
    if ((tid & 63) == 0) s_part[tid >> 6] = ss;
    __syncthreads();
    const float total = s_part[0] + s_part[1] + s_part[2] + s_part[3];
    const float inv = 1.0f / (sqrtf(total) + EPS_);

    // output pointers (flat concatenation in return order)
    f32x4* out_sel = (f32x4*)out;                                            // [B][D]
    f32x4* out_rep = (f32x4*)(out + (size_t)B_ * D_);                        // [B][C][D]
    f32x4* out_new = (f32x4*)(out + (size_t)B_ * D_ + (size_t)B_ * C_ * D_); // [C][D]

    const size_t rbase = (size_t)c * (D_ / 4);

    // tmp row -> out1 slab b=0 (plain store: want it resident for kernel B)
    out_rep[rbase + tid]      = t0;
    out_rep[rbase + tid + T_] = t1;

    // new_mem row
    out_new[rbase + tid]      = n0 * inv;
    out_new[rbase + tid + T_] = n1 * inv;

    // selected rows: every b with cls[b]==c gets the ORIGINAL memory row
    unsigned long long mm = mask;
    while (mm) {
        const int b = __ffsll(mm) - 1;
        mm &= mm - 1;
        const size_t base = (size_t)b * (D_ / 4);
        out_sel[base + tid]      = m0;
        out_sel[base + tid + T_] = m1;
    }
}

// ---------------------------------------------------------------------------
// Kernel B: replicate out1 slab 0 -> slabs 1..63. Fill-shaped: consecutive
// blocks write consecutive 8 KB rows; reads of slab 0 (12.3 MB) hit MALL.
// ---------------------------------------------------------------------------
__global__ __launch_bounds__(T_) void mb_replicate(float* __restrict__ out)
{
    const int c   = blockIdx.x;
    const int by  = blockIdx.y;
    const int tid = threadIdx.x;

    f32x4* rep = (f32x4*)(out + (size_t)B_ * D_);
    const size_t slab  = (size_t)C_ * (D_ / 4);
    const size_t rbase = (size_t)c * (D_ / 4);

    // read the tmp row once (2 float4 per thread)
    f32x4 v0 = rep[rbase + tid];
    f32x4 v1 = rep[rbase + tid + T_];

    const int b0 = 1 + by * REP_PER_BLK;
    #pragma unroll
    for (int k = 0; k < REP_PER_BLK; ++k) {
        const size_t dst = (size_t)(b0 + k) * slab + rbase;
        rep[dst + tid]      = v0;
        rep[dst + tid + T_] = v1;
    }
}

extern "C" void kernel_launch(void* const* d_in, const int* in_sizes, int n_in,
                              void* d_out, int out_size, void* d_ws, size_t ws_size,
                              hipStream_t stream) {
    const float* x   = (const float*)d_in[0];
    const int*   cls = (const int*)  d_in[1];
    const float* mem = (const float*)d_in[2];
    float*       out = (float*)d_out;

    mb_prep<<<C_, T_, 0, stream>>>(x, cls, mem, out);
    mb_replicate<<<dim3(C_, REP_GRID_Y), T_, 0, stream>>>(out);
}